// Round 5
// baseline (136.265 us; speedup 1.0000x reference)
//
#include <hip/hip_runtime.h>
#include <math.h>

#define B 8
#define C 32
#define H 384
#define W 384
#define HW (H*W)

typedef float f4 __attribute__((ext_vector_type(4)));
typedef float f2 __attribute__((ext_vector_type(2)));

// tanh via fast exp: tanh(x) = 1 - 2/(exp(2x)+1). ~1e-6 rel err; offsets only
// shift sample coords so downstream error is negligible.
__device__ __forceinline__ float fast_tanh(float v) {
    float t = __expf(2.0f * v);
    return 1.0f - 2.0f / (t + 1.0f);
}

// Reflection over [-0.5, size-0.5] then clip. Drift bound |ix - w| <= 1.503
// guarantees xr = |ix+0.5| < 2*size, so one fold suffices (no fmod).
__device__ __forceinline__ float reflect_fast(float coord, float span) {
    float xr = fabsf(coord + 0.5f);
    float out = (xr < span) ? (xr - 0.5f) : (2.0f * span - xr - 0.5f);
    return fminf(fmaxf(out, 0.0f), span - 1.0f);
}

// ---------------- offset kernel (v5) ----------------
// 64x32 tile, 256 threads, each 4 cols x 2 rows. Stage 34x72 (rows
// [h0-1,h0+33), cols [w0-4,w0+68)) with float4 loads, zero-padded.
// Double-buffered LDS, 1 barrier/channel.
#define K1_ROWS 34
#define K1_STR 72
#define K1_F4R 18
#define K1_LOADS (K1_ROWS * K1_F4R)   // 612

__global__ __launch_bounds__(256) void offset_kernel(
        const float* __restrict__ x,
        const float* __restrict__ ow,
        const float* __restrict__ ob,
        float2* __restrict__ ws) {
    __shared__ float xs[2][K1_ROWS * K1_STR];

    const int tid = threadIdx.x;
    const int b_ = blockIdx.z;
    const int h0 = blockIdx.y * 32;
    const int w0 = blockIdx.x * 64;
    const float* xb = x + (size_t)b_ * C * HW;

    // c-invariant staging descriptors
    int  g_off[3], l_off[3];
    bool g_ok[3], slot[3];
    #pragma unroll
    for (int k = 0; k < 3; ++k) {
        int idx = tid + k * 256;
        slot[k] = (idx < K1_LOADS);
        int row = idx / K1_F4R, k4 = idx - row * K1_F4R;
        int grow = h0 - 1 + row;
        int gcol = w0 - 4 + k4 * 4;
        g_ok[k] = slot[k] && grow >= 0 && grow < H && gcol >= 0 && (gcol + 3) < W;
        g_off[k] = max(grow, 0) * W + max(gcol, 0);
        l_off[k] = row * K1_STR + k4 * 4;
    }

    f4 stg[3];
#define K1_LOAD(cc) do {                                                    \
        const float* xc_ = xb + (size_t)(cc) * HW;                          \
        _Pragma("unroll")                                                   \
        for (int k = 0; k < 3; ++k)                                         \
            stg[k] = g_ok[k] ? *(const f4*)(xc_ + g_off[k]) : (f4)0.0f;     \
    } while (0)
#define K1_WRITE(bufi) do {                                                 \
        float* dst_ = xs[bufi];                                             \
        _Pragma("unroll")                                                   \
        for (int k = 0; k < 3; ++k)                                         \
            if (slot[k]) *(f4*)&dst_[l_off[k]] = stg[k];                    \
    } while (0)

    K1_LOAD(0);
    K1_WRITE(0);
    __syncthreads();

    const int tx4 = (tid & 15) * 4;
    const int ty2 = (tid >> 4) * 2;

    float acc[2][2][4];
    {
        float b0 = ob[0], b1 = ob[1];
        #pragma unroll
        for (int j = 0; j < 2; ++j)
            #pragma unroll
            for (int q = 0; q < 4; ++q) { acc[0][j][q] = b0; acc[1][j][q] = b1; }
    }

    for (int c = 0; c < C; ++c) {
        if (c + 1 < C) K1_LOAD(c + 1);

        const float* wap = ow + c * 9;
        const float* wbp = ow + (C + c) * 9;
        float wA[9], wB[9];
        #pragma unroll
        for (int k = 0; k < 9; ++k) { wA[k] = wap[k]; wB[k] = wbp[k]; }

        const float* buf = xs[c & 1];
        #pragma unroll
        for (int r = 0; r < 4; ++r) {
            int base = (ty2 + r) * K1_STR + tx4;
            f4 A = *(const f4*)&buf[base];
            f4 Bv = *(const f4*)&buf[base + 4];
            float Cv = buf[base + 8];
            float in[6] = {A.w, Bv.x, Bv.y, Bv.z, Bv.w, Cv};
            #pragma unroll
            for (int ky = 0; ky < 3; ++ky) {
                int j = r - ky;
                if (j < 0 || j > 1) continue;
                #pragma unroll
                for (int q = 0; q < 4; ++q) {
                    acc[0][j][q] = fmaf(in[q], wA[ky*3+0], fmaf(in[q+1], wA[ky*3+1], fmaf(in[q+2], wA[ky*3+2], acc[0][j][q])));
                    acc[1][j][q] = fmaf(in[q], wB[ky*3+0], fmaf(in[q+1], wB[ky*3+1], fmaf(in[q+2], wB[ky*3+2], acc[1][j][q])));
                }
            }
        }

        if (c + 1 < C) K1_WRITE((c + 1) & 1);
        __syncthreads();
    }

    const float sx = (float)W / (float)(W - 1);
    const float sy = (float)H / (float)(H - 1);
    #pragma unroll
    for (int j = 0; j < 2; ++j) {
        int hh = h0 + ty2 + j;
        float ixr[4], iyr[4];
        #pragma unroll
        for (int q = 0; q < 4; ++q) {
            float ww = (float)(w0 + tx4 + q);
            float fx = ww + fast_tanh(acc[0][j][q]);
            float fy = (float)hh + fast_tanh(acc[1][j][q]);
            ixr[q] = reflect_fast(fx * sx - 0.5f, (float)W);
            iyr[q] = reflect_fast(fy * sy - 0.5f, (float)H);
        }
        f4* p = (f4*)(ws + (size_t)b_ * HW + (size_t)hh * W + (w0 + tx4));
        f4 o0 = {ixr[0], iyr[0], ixr[1], iyr[1]};
        f4 o1 = {ixr[2], iyr[2], ixr[3], iyr[3]};
        p[0] = o0;
        p[1] = o1;
    }
}

// ---------------- sample + depthwise conv kernel (v5) ----------------
// 64x16 tile, NC=16 channels/block. Meta (tap addr, wx, wy) in REGISTERS.
// xt: 22x72 staged x window (clamped loads — reflection keeps taps in-image
// so clamped garbage is only ever multiplied by weight 0). xd: sampled tile.
// 2 barriers per channel; nt stores for out.
#define NC 16
#define XT_ROWS 22
#define XT_STR 72
#define XT_LOADS (XT_ROWS * 18)        // 396
#define XD_STR 68
#define META_N (18 * 66)               // 1188

__global__ __launch_bounds__(256) void sample_dw_kernel(
        const float* __restrict__ x,
        const float2* __restrict__ ws,
        const float* __restrict__ dww,
        float* __restrict__ out) {
    __shared__ float xt[XT_ROWS * XT_STR];   // 6336 B
    __shared__ float xd[18 * XD_STR];        // 4896 B

    const int tid = threadIdx.x;
    const int bz = blockIdx.z;               // b*2 + cg
    const int b_ = bz >> 1;
    const int c0 = (bz & 1) * NC;
    const int h0 = blockIdx.y * 16;
    const int w0 = blockIdx.x * 64;

    const float* xb = x + ((size_t)b_ * C + c0) * HW;
    const float2* wsb = ws + (size_t)b_ * HW;

    // c-invariant stage descriptors
    int s_goff[2], s_loff[2];
    bool s_ok[2];
    #pragma unroll
    for (int k = 0; k < 2; ++k) {
        int idx = tid + k * 256;
        s_ok[k] = (idx < XT_LOADS);
        int row = idx / 18, k4 = idx - row * 18;
        int grow = min(max(h0 - 3 + row, 0), H - 1);
        int gcol = min(max(w0 - 4 + k4 * 4, 0), W - 4);
        s_goff[k] = grow * W + gcol;
        s_loff[k] = row * XT_STR + k4 * 4;
    }

    // prefetch channel 0
    f4 pf[2];
    #pragma unroll
    for (int k = 0; k < 2; ++k)
        pf[k] = s_ok[k] ? *(const f4*)(xb + s_goff[k]) : (f4)0.0f;

    // per-pixel meta in registers (same thread writes & consumes index i)
    const int addr_base = (h0 - 3) * XT_STR + (w0 - 4);
    int   ma[5], xdo[5];
    float mwx[5], mwy[5];
    #pragma unroll
    for (int k = 0; k < 5; ++k) {
        int i = tid + k * 256;
        ma[k] = -1; xdo[k] = 0; mwx[k] = 0.f; mwy[k] = 0.f;
        if (i < META_N) {
            int r = i / 66, q = i - r * 66;
            xdo[k] = r * XD_STR + q;
            int hp = h0 - 1 + r, wp = w0 - 1 + q;
            if (hp >= 0 && hp < H && wp >= 0 && wp < W) {
                float2 crd = wsb[hp * W + wp];
                float ix0f = floorf(crd.x), iy0f = floorf(crd.y);
                mwx[k] = crd.x - ix0f;
                mwy[k] = crd.y - iy0f;
                int ix0 = min(max((int)ix0f, 0), W - 1);
                int iy0 = min(max((int)iy0f, 0), H - 1);
                ma[k] = iy0 * XT_STR + ix0 - addr_base;
            } else {
                ma[k] = -2;                   // in tile, zero value
            }
        }
    }

    const int tx4 = (tid & 15) * 4;
    const int ty  = tid >> 4;

    for (int cc = 0; cc < NC; ++cc) {
        // regs -> xt
        #pragma unroll
        for (int k = 0; k < 2; ++k)
            if (s_ok[k]) *(f4*)&xt[s_loff[k]] = pf[k];
        __syncthreads();

        // prefetch next channel (overlaps sample+conv)
        if (cc + 1 < NC) {
            const float* xc = xb + (size_t)(cc + 1) * HW;
            #pragma unroll
            for (int k = 0; k < 2; ++k)
                pf[k] = s_ok[k] ? *(const f4*)(xc + s_goff[k]) : (f4)0.0f;
        }

        // bilinear sample xt -> xd
        #pragma unroll
        for (int k = 0; k < 5; ++k) {
            int a = ma[k];
            if (a != -1) {
                float v = 0.0f;
                if (a >= 0) {
                    float wx1 = mwx[k], wy1 = mwy[k];
                    float wx0 = 1.0f - wx1, wy0 = 1.0f - wy1;
                    float v00 = xt[a];
                    float v01 = xt[a + 1];
                    float v10 = xt[a + XT_STR];
                    float v11 = xt[a + XT_STR + 1];
                    v = (v00 * wx0 + v01 * wx1) * wy0 + (v10 * wx0 + v11 * wx1) * wy1;
                }
                xd[xdo[k]] = v;
            }
        }

        float wk[9];
        const float* wc = dww + (size_t)(c0 + cc) * 9;
        #pragma unroll
        for (int i = 0; i < 9; ++i) wk[i] = wc[i];

        __syncthreads();

        // 3x3 depthwise conv: 1 row x 4 cols per thread
        float a4[4] = {0.f, 0.f, 0.f, 0.f};
        #pragma unroll
        for (int ky = 0; ky < 3; ++ky) {
            int base = (ty + ky) * XD_STR + tx4;
            f4 A = *(const f4*)&xd[base];
            f2 D = *(const f2*)&xd[base + 4];
            float in[6] = {A.x, A.y, A.z, A.w, D.x, D.y};
            #pragma unroll
            for (int q = 0; q < 4; ++q)
                a4[q] = fmaf(in[q], wk[ky*3+0], fmaf(in[q+1], wk[ky*3+1], fmaf(in[q+2], wk[ky*3+2], a4[q])));
        }
        f4 res = {fmaxf(a4[0], 0.f), fmaxf(a4[1], 0.f), fmaxf(a4[2], 0.f), fmaxf(a4[3], 0.f)};
        float* op = out + ((size_t)b_ * C + c0 + cc) * HW + (size_t)(h0 + ty) * W + (w0 + tx4);
        __builtin_nontemporal_store(res, (f4*)op);
        // next iteration's xt overwrite is safe: all samples of this xt
        // finished before the barrier above; conv only touches xd.
    }
}

extern "C" void kernel_launch(void* const* d_in, const int* in_sizes, int n_in,
                              void* d_out, int out_size, void* d_ws, size_t ws_size,
                              hipStream_t stream) {
    const float* x   = (const float*)d_in[0];
    const float* ow  = (const float*)d_in[1];
    const float* ob  = (const float*)d_in[2];
    const float* dww = (const float*)d_in[3];
    float* out = (float*)d_out;
    float2* ws = (float2*)d_ws;

    dim3 g1(W / 64, H / 32, B);
    offset_kernel<<<g1, 256, 0, stream>>>(x, ow, ob, ws);

    dim3 g2(W / 64, H / 16, B * (C / NC));
    sample_dw_kernel<<<g2, 256, 0, stream>>>(x, ws, dww, out);
}